// Round 4
// baseline (246.450 us; speedup 1.0000x reference)
//
#include <hip/hip_runtime.h>

constexpr int F = 2048;          // NUM_FEATURES
constexpr int NROWS = 8192;      // rows
constexpr float EPS = 1e-6f;
constexpr int STRIDE4 = F / 4;   // 512 float4 per row
constexpr unsigned NBLOCKS = 8u * (NROWS / 64);   // 1024 = exactly 4 blocks/CU on 256 CUs

typedef float nfloat4 __attribute__((ext_vector_type(4)));  // native vec for nontemporal builtins

// ---------------------------------------------------------------------------
// Fused single-pass kernel with a software grid barrier.
//
// Grid (8, 128) = 1024 blocks x 256 threads. __launch_bounds__(256, 4) caps
// VGPR at 128 so 4 blocks/CU are guaranteed co-resident (1024 = 256 CU x 4),
// which the spin barrier requires. LDS = 12 KB/block (4 x 12 KB << 160 KB/CU).
//
// Phase 1: block covers 64 float4-columns x 64 rows; thread (lc,sg) holds its
//   16 float4 of x in REGISTERS while accumulating sum/sumsq; LDS-reduce the
//   4 row-subgroups; 64 threads/block do the 8 atomicAdds (524k total).
// Barrier: each block bumps a device counter after its atomics are drained
//   (__syncthreads emits s_waitcnt vmcnt(0), so the atomics are performed);
//   thread 0 spins on agent-scope acquire loads with s_sleep backoff.
//   Bounded spin: a failure degrades to a wrong answer, not a hang.
// Phase 2: sg==0 threads read their column's sums with agent-scope loads
//   (bypass possibly-stale per-XCD cache), compute rstd / -mean*rstd, share
//   via LDS; all threads normalize their register-held x and stream out with
//   non-temporal stores. x is read from HBM exactly once.
// ---------------------------------------------------------------------------
__global__ __launch_bounds__(256, 4) void fused_kernel(const float* __restrict__ x,
                                                       float* __restrict__ acc,
                                                       unsigned* __restrict__ ctr,
                                                       float* __restrict__ out) {
    __shared__ float4 lS[3 * 64];
    __shared__ float4 lQ[3 * 64];

    const int lc = threadIdx.x & 63;
    const int sg = threadIdx.x >> 6;
    const int c4 = blockIdx.x * 64 + lc;
    const int row0 = blockIdx.y * 64 + sg * 16;

    const nfloat4* __restrict__ xv = reinterpret_cast<const nfloat4*>(x);
    const size_t base = (size_t)row0 * STRIDE4 + (size_t)c4;

    nfloat4 v[16];
    float4 s = make_float4(0.f, 0.f, 0.f, 0.f);
    float4 q = make_float4(0.f, 0.f, 0.f, 0.f);

#pragma unroll
    for (int r = 0; r < 16; ++r) {
        const nfloat4 t = __builtin_nontemporal_load(&xv[base + (size_t)r * STRIDE4]);
        v[r] = t;
        s.x += t.x;  s.y += t.y;  s.z += t.z;  s.w += t.w;
        q.x = fmaf(t.x, t.x, q.x);
        q.y = fmaf(t.y, t.y, q.y);
        q.z = fmaf(t.z, t.z, q.z);
        q.w = fmaf(t.w, t.w, q.w);
    }

    if (sg != 0) {
        lS[(sg - 1) * 64 + lc] = s;
        lQ[(sg - 1) * 64 + lc] = q;
    }
    __syncthreads();

    if (sg == 0) {
#pragma unroll
        for (int k = 0; k < 3; ++k) {
            const float4 t = lS[k * 64 + lc];
            const float4 u = lQ[k * 64 + lc];
            s.x += t.x;  s.y += t.y;  s.z += t.z;  s.w += t.w;
            q.x += u.x;  q.y += u.y;  q.z += u.z;  q.w += u.w;
        }
        float* __restrict__ sum   = acc;
        float* __restrict__ sumsq = acc + F;
        const int c = c4 * 4;
        atomicAdd(&sum[c + 0], s.x);
        atomicAdd(&sum[c + 1], s.y);
        atomicAdd(&sum[c + 2], s.z);
        atomicAdd(&sum[c + 3], s.w);
        atomicAdd(&sumsq[c + 0], q.x);
        atomicAdd(&sumsq[c + 1], q.y);
        atomicAdd(&sumsq[c + 2], q.z);
        atomicAdd(&sumsq[c + 3], q.w);
    }

    // ---- software grid barrier ----
    __syncthreads();   // s_waitcnt vmcnt(0): this block's atomics are performed
    if (threadIdx.x == 0) {
        __threadfence();
        atomicAdd(ctr, 1u);
        for (int it = 0; it < (1 << 22); ++it) {   // bounded: fail fast, don't hang
            if (__hip_atomic_load(ctr, __ATOMIC_ACQUIRE, __HIP_MEMORY_SCOPE_AGENT) >= NBLOCKS)
                break;
            __builtin_amdgcn_s_sleep(32);
        }
    }
    __syncthreads();

    // ---- phase 2: stats (64 threads), broadcast via LDS ----
    if (sg == 0) {
        const int c = c4 * 4;
        float S1[4], S2[4];
#pragma unroll
        for (int k = 0; k < 4; ++k) {
            S1[k] = __hip_atomic_load(&acc[c + k],     __ATOMIC_RELAXED, __HIP_MEMORY_SCOPE_AGENT);
            S2[k] = __hip_atomic_load(&acc[F + c + k], __ATOMIC_RELAXED, __HIP_MEMORY_SCOPE_AGENT);
        }
        const float invN  = 1.0f / (float)NROWS;
        const float invN1 = 1.0f / (float)(NROWS - 1);
        float4 r4, b4;
        {
            const float mx = S1[0] * invN;
            const float my = S1[1] * invN;
            const float mz = S1[2] * invN;
            const float mw = S1[3] * invN;
            const float vx = fmaxf((S2[0] - S1[0] * mx) * invN1, 0.0f);
            const float vy = fmaxf((S2[1] - S1[1] * my) * invN1, 0.0f);
            const float vz = fmaxf((S2[2] - S1[2] * mz) * invN1, 0.0f);
            const float vw = fmaxf((S2[3] - S1[3] * mw) * invN1, 0.0f);
            r4.x = rsqrtf(vx + EPS);
            r4.y = rsqrtf(vy + EPS);
            r4.z = rsqrtf(vz + EPS);
            r4.w = rsqrtf(vw + EPS);
            b4.x = -mx * r4.x;
            b4.y = -my * r4.y;
            b4.z = -mz * r4.z;
            b4.w = -mw * r4.w;
        }
        lS[lc] = r4;
        lQ[lc] = b4;
    }
    __syncthreads();

    const float4 r4 = lS[lc];
    const float4 b4 = lQ[lc];
    nfloat4* __restrict__ ov = reinterpret_cast<nfloat4*>(out);
#pragma unroll
    for (int r = 0; r < 16; ++r) {
        const nfloat4 t = v[r];
        nfloat4 o;
        o.x = fmaf(t.x, r4.x, b4.x);
        o.y = fmaf(t.y, r4.y, b4.y);
        o.z = fmaf(t.z, r4.z, b4.z);
        o.w = fmaf(t.w, r4.w, b4.w);
        __builtin_nontemporal_store(o, &ov[base + (size_t)r * STRIDE4]);
    }
}

extern "C" void kernel_launch(void* const* d_in, const int* in_sizes, int n_in,
                              void* d_out, int out_size, void* d_ws, size_t ws_size,
                              hipStream_t stream) {
    const float* x = (const float*)d_in[0];
    // running_mean / running_var are wiped by the Welford recurrence (n=1 / n=2).
    float* out    = (float*)d_out;
    float* acc    = (float*)d_ws;                     // [0:F) sum, [F:2F) sumsq
    unsigned* ctr = (unsigned*)(acc + 2 * F);         // barrier counter

    (void)hipMemsetAsync(d_ws, 0, (2 * F + 4) * sizeof(float), stream);

    fused_kernel<<<dim3(8, NROWS / 64), 256, 0, stream>>>(x, acc, ctr, out);
}

// Round 5
// 130.841 us; speedup vs baseline: 1.8836x; 1.8836x over previous
//
#include <hip/hip_runtime.h>

constexpr int F = 2048;          // NUM_FEATURES
constexpr int NROWS = 8192;      // rows
constexpr float EPS = 1e-6f;
constexpr int STRIDE4 = F / 4;   // 512 float4 per row

typedef float nfloat4 __attribute__((ext_vector_type(4)));  // native vec for nontemporal builtin

// ---------------------------------------------------------------------------
// Pass 1: per-column partial sum / sumsq.
// Grid (8, 128), block 256. Block covers 64 float4-columns x 64 rows.
// Threads: lc = tid&63 (column), sg = tid>>6 (row subgroup, 16 rows each).
// LDS reduces the 4 subgroups so only 64 threads/block do atomics
// (1024 blocks * 64 thr * 8 atomics = 524k atomic float adds).
// Plain (cache-allocating) loads on purpose: x must land in L3 so the
// norm pass's re-read is L3-hot.
// ---------------------------------------------------------------------------
__global__ __launch_bounds__(256) void reduce_kernel(const float* __restrict__ x,
                                                     float* __restrict__ acc) {
    __shared__ float4 lS[3 * 64];
    __shared__ float4 lQ[3 * 64];

    const int lc = threadIdx.x & 63;
    const int sg = threadIdx.x >> 6;
    const int c4 = blockIdx.x * 64 + lc;
    const int row0 = blockIdx.y * 64 + sg * 16;
    const float4* __restrict__ xv = reinterpret_cast<const float4*>(x);

    float4 s = make_float4(0.f, 0.f, 0.f, 0.f);
    float4 q = make_float4(0.f, 0.f, 0.f, 0.f);

    size_t base = (size_t)row0 * STRIDE4 + (size_t)c4;
#pragma unroll
    for (int r = 0; r < 16; ++r) {
        float4 v = xv[base + (size_t)r * STRIDE4];
        s.x += v.x;  s.y += v.y;  s.z += v.z;  s.w += v.w;
        q.x = fmaf(v.x, v.x, q.x);
        q.y = fmaf(v.y, v.y, q.y);
        q.z = fmaf(v.z, v.z, q.z);
        q.w = fmaf(v.w, v.w, q.w);
    }

    if (sg != 0) {
        lS[(sg - 1) * 64 + lc] = s;
        lQ[(sg - 1) * 64 + lc] = q;
    }
    __syncthreads();

    if (sg == 0) {
#pragma unroll
        for (int k = 0; k < 3; ++k) {
            float4 t = lS[k * 64 + lc];
            float4 u = lQ[k * 64 + lc];
            s.x += t.x;  s.y += t.y;  s.z += t.z;  s.w += t.w;
            q.x += u.x;  q.y += u.y;  q.z += u.z;  q.w += u.w;
        }
        float* __restrict__ sum   = acc;
        float* __restrict__ sumsq = acc + F;
        const int c = c4 * 4;
        atomicAdd(&sum[c + 0], s.x);
        atomicAdd(&sum[c + 1], s.y);
        atomicAdd(&sum[c + 2], s.z);
        atomicAdd(&sum[c + 3], s.w);
        atomicAdd(&sumsq[c + 0], q.x);
        atomicAdd(&sumsq[c + 1], q.y);
        atomicAdd(&sumsq[c + 2], q.z);
        atomicAdd(&sumsq[c + 3], q.w);
    }
}

// ---------------------------------------------------------------------------
// Pass 2 (fused finalize + normalize).
// Same geometry as reduce. Each thread computes its column's rstd/bias inline
// from acc (2 float4, L2-hot), then streams out = fma(x, r, b).
// x re-read is mostly L3-hit (64 MiB << 256 MiB L3); out stores are
// non-temporal so the 64 MiB write stream doesn't evict x from L3.
// ---------------------------------------------------------------------------
__global__ __launch_bounds__(256) void norm_kernel(const float* __restrict__ x,
                                                   const float* __restrict__ acc,
                                                   float* __restrict__ out) {
    const int lc = threadIdx.x & 63;
    const int sg = threadIdx.x >> 6;
    const int c4 = blockIdx.x * 64 + lc;
    const int row0 = blockIdx.y * 64 + sg * 16;
    const float4* __restrict__ xv = reinterpret_cast<const float4*>(x);
    nfloat4* __restrict__ ov      = reinterpret_cast<nfloat4*>(out);

    // Inline finalize for this thread's column.
    const float4 S1 = reinterpret_cast<const float4*>(acc)[c4];
    const float4 S2 = reinterpret_cast<const float4*>(acc + F)[c4];

    const float invN  = 1.0f / (float)NROWS;
    const float invN1 = 1.0f / (float)(NROWS - 1);

    float4 r4, b4;
    {
        const float mx = S1.x * invN;
        const float my = S1.y * invN;
        const float mz = S1.z * invN;
        const float mw = S1.w * invN;
        const float vx = fmaxf((S2.x - S1.x * mx) * invN1, 0.0f);
        const float vy = fmaxf((S2.y - S1.y * my) * invN1, 0.0f);
        const float vz = fmaxf((S2.z - S1.z * mz) * invN1, 0.0f);
        const float vw = fmaxf((S2.w - S1.w * mw) * invN1, 0.0f);
        r4.x = rsqrtf(vx + EPS);
        r4.y = rsqrtf(vy + EPS);
        r4.z = rsqrtf(vz + EPS);
        r4.w = rsqrtf(vw + EPS);
        b4.x = -mx * r4.x;
        b4.y = -my * r4.y;
        b4.z = -mz * r4.z;
        b4.w = -mw * r4.w;
    }

    const size_t base = (size_t)row0 * STRIDE4 + (size_t)c4;
#pragma unroll
    for (int r = 0; r < 16; ++r) {
        const size_t idx = base + (size_t)r * STRIDE4;
        const float4 t = xv[idx];
        nfloat4 o;
        o.x = fmaf(t.x, r4.x, b4.x);
        o.y = fmaf(t.y, r4.y, b4.y);
        o.z = fmaf(t.z, r4.z, b4.z);
        o.w = fmaf(t.w, r4.w, b4.w);
        __builtin_nontemporal_store(o, &ov[idx]);
    }
}

extern "C" void kernel_launch(void* const* d_in, const int* in_sizes, int n_in,
                              void* d_out, int out_size, void* d_ws, size_t ws_size,
                              hipStream_t stream) {
    const float* x = (const float*)d_in[0];
    // running_mean / running_var are wiped by the Welford recurrence (n=1 / n=2).
    float* out = (float*)d_out;
    float* acc = (float*)d_ws;   // [0:F) sum, [F:2F) sumsq

    (void)hipMemsetAsync(d_ws, 0, 2 * F * sizeof(float), stream);

    reduce_kernel<<<dim3(8, NROWS / 64), 256, 0, stream>>>(x, acc);
    norm_kernel<<<dim3(8, NROWS / 64), 256, 0, stream>>>(x, acc, out);
}